// Round 1
// baseline (769.236 us; speedup 1.0000x reference)
//
#include <hip/hip_runtime.h>

// Sorted scatter-add as a two-pass gather:
//  Pass A: build CSR row_ptr[N+1] from the sorted index (direct boundary
//          writes, no search): row_ptr[n] = lower_bound(idx, n).
//  Pass B: one 64-lane wave per TWO output rows (32 lanes/row, float4/lane:
//          16 B/lane matches the measured 6.3 TB/s HBM-ceiling pattern).
//          2 cached loads for segment bounds, stream self row + value
//          segment (4 independent float4 loads in flight), single coalesced
//          float4 store.

typedef float f4 __attribute__((ext_vector_type(4)));
typedef float f2 __attribute__((ext_vector_type(2)));

__global__ __launch_bounds__(256) void build_row_ptr_kernel(
    const int* __restrict__ idx,     // [M], sorted ascending, values in [0,N)
    int*       __restrict__ row_ptr, // [N+1]
    int N, int M)
{
    int i = blockIdx.x * blockDim.x + threadIdx.x;
    if (i > M) return;
    if (i == M) {
        // rows after the last index, plus the sentinel row_ptr[N] = M
        int prev = idx[M - 1];
        for (int n = prev + 1; n <= N; ++n) row_ptr[n] = M;
        return;
    }
    int cur  = idx[i];
    int prev = (i == 0) ? -1 : idx[i - 1];
    for (int n = prev + 1; n <= cur; ++n) row_ptr[n] = i;
}

__global__ __launch_bounds__(256) void gather_add_kernel(
    const float* __restrict__ self_t,   // [N, 128]
    const float* __restrict__ value,    // [M, 128]
    const int*   __restrict__ row_ptr,  // [N+1]
    float*       __restrict__ out,      // [N, 128]
    int N)
{
    const int D4 = 32;  // float4 elements per row (D=128 floats)
    int wave_id = (int)((blockIdx.x * (unsigned)blockDim.x + threadIdx.x) >> 6);
    int lane    = threadIdx.x & 63;
    int half    = lane >> 5;        // which of the wave's two rows
    int lr      = lane & 31;        // lane within the row
    int n = wave_id * 2 + half;
    if (n >= N) return;

    int lo  = row_ptr[n];
    int hi  = row_ptr[n + 1];
    int cnt = hi - lo;

    const f4* selfp = (const f4*)self_t + (size_t)n * D4 + lr;
    f4 acc = __builtin_nontemporal_load(selfp);

    const f4* vp = (const f4*)value + (size_t)lo * D4 + lr;

    // Unrolled: 4 independent 16B loads in flight, serial adds (matches ref
    // order: increasing i within the segment).
    while (cnt >= 4) {
        f4 v0 = __builtin_nontemporal_load(vp);
        f4 v1 = __builtin_nontemporal_load(vp + D4);
        f4 v2 = __builtin_nontemporal_load(vp + 2 * D4);
        f4 v3 = __builtin_nontemporal_load(vp + 3 * D4);
        acc += v0; acc += v1; acc += v2; acc += v3;
        vp  += 4 * D4;
        cnt -= 4;
    }
    while (cnt > 0) {
        f4 v = __builtin_nontemporal_load(vp);
        acc += v;
        vp  += D4;
        --cnt;
    }

    f4* outp = (f4*)out + (size_t)n * D4 + lr;
    __builtin_nontemporal_store(acc, outp);
}

// Fallback (ws too small): round-1 binary-search kernel, known-correct.
__global__ __launch_bounds__(256) void scatter_add_bsearch_kernel(
    const float* __restrict__ self_t, const float* __restrict__ value,
    const int* __restrict__ idx, float* __restrict__ out, int N, int M)
{
    const int D2 = 64;
    int wave_id = (int)((blockIdx.x * (unsigned)blockDim.x + threadIdx.x) >> 6);
    int lane    = threadIdx.x & 63;
    if (wave_id >= N) return;
    const int n = wave_id;
    int lo = 0, hi = M;
    while (lo < hi) { int mid = (lo + hi) >> 1; if (idx[mid] < n) lo = mid + 1; else hi = mid; }
    const int seg_lo = lo;
    hi = M;
    while (lo < hi) { int mid = (lo + hi) >> 1; if (idx[mid] < n + 1) lo = mid + 1; else hi = mid; }
    const int seg_hi = lo;
    const f2* selfp = (const f2*)self_t + (size_t)n * D2 + lane;
    f2 acc = *selfp;
    const f2* vp = (const f2*)value + (size_t)seg_lo * D2 + lane;
    for (int i = seg_lo; i < seg_hi; ++i, vp += D2) { f2 v = *vp; acc += v; }
    f2* outp = (f2*)out + (size_t)n * D2 + lane;
    *outp = acc;
}

extern "C" void kernel_launch(void* const* d_in, const int* in_sizes, int n_in,
                              void* d_out, int out_size, void* d_ws, size_t ws_size,
                              hipStream_t stream)
{
    const float* self_t = (const float*)d_in[0];
    const float* value  = (const float*)d_in[1];
    const int*   idx    = (const int*)d_in[2];
    float* out = (float*)d_out;

    const int D = 128;
    const int N = out_size / D;          // 262144
    const int M = in_sizes[2];           // 1048576

    const size_t row_ptr_bytes = (size_t)(N + 1) * sizeof(int);

    if (ws_size >= row_ptr_bytes) {
        int* row_ptr = (int*)d_ws;

        int blockA = 256;
        int gridA  = (M + 1 + blockA - 1) / blockA;
        build_row_ptr_kernel<<<gridA, blockA, 0, stream>>>(idx, row_ptr, N, M);

        int blockB = 256;
        int waves  = (N + 1) / 2;                      // 2 rows per wave
        int waves_per_block = blockB / 64;
        int gridB  = (waves + waves_per_block - 1) / waves_per_block;
        gather_add_kernel<<<gridB, blockB, 0, stream>>>(self_t, value, row_ptr, out, N);
    } else {
        int block = 256;
        int waves_per_block = block / 64;
        int grid = (N + waves_per_block - 1) / waves_per_block;
        scatter_add_bsearch_kernel<<<grid, block, 0, stream>>>(self_t, value, idx, out, N, M);
    }
}